// Round 1
// baseline (882.602 us; speedup 1.0000x reference)
//
#include <hip/hip_runtime.h>

// Ensemble of 8 LSTMs (H=64, input=1) over T=1024 steps, B=128, then (B,T)@Wl^T+bl.
//
// Design: 512 blocks = 8 L x 64 batch-pairs, 256 threads (4 waves).
//  - Whh row (64 fp32) lives in VGPRs: lane j of wave w owns gate-row w*64+j. Loaded once.
//  - h (2 batches x 64) lives in LDS; matvec reads are uniform-address (broadcast, conflict-free).
//  - wave w produces gate-type w for both batches; epilogue: all 4 waves, 32 lanes each,
//    update cell state (c in a register per lane).
//  - per-(l,b) output partial acc_a = sum_t h63[t]*Wl[a,t] kept in registers of lanes 0..7
//    of waves 0..1, written to d_ws; reduce_kernel sums over L and adds bl.

#define LENA 8
#define NB 128
#define NT 1024
#define NH 64
#define BPB 2   // batches per block

__device__ __forceinline__ float fast_sigmoid(float x) {
    return __builtin_amdgcn_rcpf(1.0f + __builtin_amdgcn_exp2f(-1.44269504f * x));
}
__device__ __forceinline__ float fast_tanh(float x) {
    // tanh(x) = 1 - 2/(1+exp(2x));  exp(2x) = exp2(2.88539008*x)
    return 1.0f - 2.0f * __builtin_amdgcn_rcpf(1.0f + __builtin_amdgcn_exp2f(2.88539008f * x));
}

__global__ __launch_bounds__(256) void lstm_kernel(
    const float* __restrict__ x, const float* __restrict__ hn,
    const float* __restrict__ Wih, const float* __restrict__ Whh,
    const float* __restrict__ bih, const float* __restrict__ bhh,
    const float* __restrict__ Wl, float* __restrict__ ws)
{
    __shared__ float x_lds[BPB][NT];                    // 8 KB
    __shared__ float wl_lds[NT][LENA];                  // 32 KB (Wl transposed)
    __shared__ __align__(16) float h_lds[BPB][NH];      // 512 B
    __shared__ float gates_lds[4][BPB][NH];             // 2 KB

    const int tid = threadIdx.x;
    const int w = tid >> 6;          // wave 0..3 = gate type i,f,g,o
    const int j = tid & 63;          // hidden unit (gate row within type)
    const int l  = blockIdx.x >> 6;  // LSTM index 0..7
    const int bg = blockIdx.x & 63;  // batch pair 0..63
    const int b0 = bg * BPB;

    // ---- one-time staging ----
    for (int i = tid; i < BPB * NT; i += 256) {
        int bb = i >> 10, t = i & (NT - 1);
        x_lds[bb][t] = x[(size_t)(b0 + bb) * NT + t];
    }
    for (int i = tid; i < NT * LENA; i += 256) {
        int a = i >> 10, t = i & (NT - 1);
        wl_lds[t][a] = Wl[a * NT + t];
    }
    for (int i = tid; i < BPB * NH; i += 256) {
        int bb = i >> 6, k = i & 63;
        h_lds[bb][k] = hn[((size_t)l * NB + b0 + bb) * NH + k];
    }

    // ---- per-lane persistent weights (Whh row in VGPRs) ----
    const int row = (w << 6) | j;                       // 0..255
    const float* wrow = Whh + ((size_t)l * 256 + row) * 64;
    float4 w4[16];
    #pragma unroll
    for (int c2 = 0; c2 < 16; ++c2) w4[c2] = reinterpret_cast<const float4*>(wrow)[c2];
    const float wih_r  = Wih[l * 256 + row];
    const float bias_r = bih[l * 256 + row] + bhh[l * 256 + row];

    // epilogue mapping: wave w -> batch (w&1), units [(w>>1)*32, +32)
    const int eb = w & 1;
    const int u0 = (w >> 1) << 5;
    const bool epi = (j < 32);
    const bool doacc = (w < BPB) && (j < LENA);
    float c_state = 0.0f;   // c0 = 0 per reference
    float pacc = 0.0f;

    __syncthreads();

    #pragma unroll 1
    for (int t = 0; t < NT; ++t) {
        // gates for both batches: row dot h  (+ x*wih + bias)
        float acc0 = fmaf(x_lds[0][t], wih_r, bias_r);
        float acc1 = fmaf(x_lds[1][t], wih_r, bias_r);
        #pragma unroll
        for (int kc = 0; kc < 16; ++kc) {
            float4 h0v = *reinterpret_cast<const float4*>(&h_lds[0][kc * 4]);
            float4 h1v = *reinterpret_cast<const float4*>(&h_lds[1][kc * 4]);
            float4 wv  = w4[kc];
            acc0 = fmaf(wv.x, h0v.x, acc0);
            acc0 = fmaf(wv.y, h0v.y, acc0);
            acc0 = fmaf(wv.z, h0v.z, acc0);
            acc0 = fmaf(wv.w, h0v.w, acc0);
            acc1 = fmaf(wv.x, h1v.x, acc1);
            acc1 = fmaf(wv.y, h1v.y, acc1);
            acc1 = fmaf(wv.z, h1v.z, acc1);
            acc1 = fmaf(wv.w, h1v.w, acc1);
        }
        gates_lds[w][0][j] = acc0;
        gates_lds[w][1][j] = acc1;
        __syncthreads();

        if (epi) {
            int u = u0 + j;
            float gi = gates_lds[0][eb][u];
            float gf = gates_lds[1][eb][u];
            float gg = gates_lds[2][eb][u];
            float go = gates_lds[3][eb][u];
            float iv = fast_sigmoid(gi);
            float fv = fast_sigmoid(gf);
            float gv = fast_tanh(gg);
            float ov = fast_sigmoid(go);
            c_state = fmaf(fv, c_state, iv * gv);
            h_lds[eb][u] = ov * fast_tanh(c_state);
        }
        __syncthreads();

        // accumulate projection with h[..,63] of this step (wave w<2 owns batch w)
        if (doacc) pacc = fmaf(h_lds[w][NH - 1], wl_lds[t][j], pacc);
    }

    if (doacc) ws[((size_t)l * NB + b0 + w) * LENA + j] = pacc;
}

__global__ __launch_bounds__(256) void reduce_kernel(
    const float* __restrict__ ws, const float* __restrict__ bl, float* __restrict__ out)
{
    int tid = blockIdx.x * 256 + threadIdx.x;    // 0..1023
    if (tid >= NB * LENA) return;
    int b = tid >> 3, a = tid & 7;
    float s = bl[a];
    #pragma unroll
    for (int l2 = 0; l2 < LENA; ++l2) s += ws[((size_t)l2 * NB + b) * LENA + a];
    out[tid] = s;
}

extern "C" void kernel_launch(void* const* d_in, const int* in_sizes, int n_in,
                              void* d_out, int out_size, void* d_ws, size_t ws_size,
                              hipStream_t stream) {
    const float* x   = (const float*)d_in[0];
    const float* hn  = (const float*)d_in[1];
    const float* Wih = (const float*)d_in[2];
    const float* Whh = (const float*)d_in[3];
    const float* bih = (const float*)d_in[4];
    const float* bhh = (const float*)d_in[5];
    const float* Wl  = (const float*)d_in[6];
    const float* bl  = (const float*)d_in[7];
    float* out = (float*)d_out;
    float* ws  = (float*)d_ws;   // needs 8*128*8*4 = 32 KB

    lstm_kernel<<<dim3(512), dim3(256), 0, stream>>>(x, hn, Wih, Whh, bih, bhh, Wl, ws);
    reduce_kernel<<<dim3(4), dim3(256), 0, stream>>>(ws, bl, out);
}

// Round 2
// 789.829 us; speedup vs baseline: 1.1175x; 1.1175x over previous
//
#include <hip/hip_runtime.h>

// Ensemble of 8 LSTMs (H=64, input dim 1) over T=1024, B=128, then (B,T)@Wl^T+bl.
//
// MFMA formulation: per (l, batch-group-of-16) chain, per step:
//   gates(16x256) = h(16x64) @ Whh^T(64x256)  via mfma_f32_16x16x32_bf16
// fp32 accuracy via 3-product bf16 split: Whi*hhi + Whi*hlo + Wlo*hhi.
// 64 blocks (8 l x 8 batch-groups), 4 waves; wave w owns units 16w..16w+15
// (gate-row tiles 64G+16w for G=i,f,g,o) -> i,f,g,o for a (batch,unit) land in
// the SAME lane (D: col=lane&15=unit-in-tile, row=(lane>>4)*4+reg=batch).
// h ping-pongs through an XOR-swizzled LDS buffer; 1 barrier/step.

#define LENA 8
#define NB 128
#define NT 1024
#define NH 64

typedef __attribute__((ext_vector_type(4))) float f32x4;
typedef __attribute__((ext_vector_type(8))) short bf16x8;

__device__ __forceinline__ short f2bf(float f) {
    unsigned u = __float_as_uint(f);
    unsigned r = (u + 0x7FFFu + ((u >> 16) & 1u)) >> 16;
    return (short)r;
}
__device__ __forceinline__ float bf2f(short s) {
    return __uint_as_float(((unsigned)(unsigned short)s) << 16);
}
__device__ __forceinline__ float fsig(float x) {
    return __builtin_amdgcn_rcpf(1.0f + __builtin_amdgcn_exp2f(-1.44269504f * x));
}
__device__ __forceinline__ float ftanh(float x) {
    return 1.0f - 2.0f * __builtin_amdgcn_rcpf(1.0f + __builtin_amdgcn_exp2f(2.88539008f * x));
}

__global__ __launch_bounds__(256, 1) void lstm_mfma_kernel(
    const float* __restrict__ x, const float* __restrict__ hn,
    const float* __restrict__ Wih, const float* __restrict__ Whh,
    const float* __restrict__ bih, const float* __restrict__ bhh,
    const float* __restrict__ Wl, float* __restrict__ ws)
{
    __shared__ float wl_lds[NT][LENA];                   // 32 KB, Wl transposed
    __shared__ __align__(16) short hbuf[2][2][16 * NH];  // [parity][hi/lo] 8 KB
    __shared__ float h63buf[2][16];

    const int tid = threadIdx.x;
    const int w  = tid >> 6;         // wave 0..3
    const int l  = tid & 63;         // lane
    const int li = blockIdx.x >> 3;  // LSTM index 0..7
    const int bg = blockIdx.x & 7;   // batch group (16 batches)

    // ---- staging ----
    for (int i = tid; i < NT * LENA; i += 256) {
        int a = i >> 10, t = i & (NT - 1);
        wl_lds[t][a] = Wl[a * NT + t];
    }
    for (int i = tid; i < 16 * NH; i += 256) {
        int b = i >> 6, u = i & 63;
        float v = hn[((size_t)li * NB + bg * 16 + b) * NH + u];
        int idx = b * 64 + ((((u >> 3) ^ (b & 7)) << 3) | (u & 7));
        short hi = f2bf(v);
        hbuf[0][0][idx] = hi;
        hbuf[0][1][idx] = f2bf(v - bf2f(hi));
    }

    // ---- per-lane persistent B fragments (Whh, bf16 hi/lo split) ----
    const int bq = l & 15, kg = l >> 4;
    bf16x8 bhf[4][2], blf[4][2];
    float biasv[4], wihv[4];
    #pragma unroll
    for (int G = 0; G < 4; ++G) {
        int row = 64 * G + 16 * w + bq;
        const float* rp = Whh + ((size_t)li * 256 + row) * 64 + kg * 8;
        #pragma unroll
        for (int kt = 0; kt < 2; ++kt) {
            const float* q = rp + kt * 32;
            #pragma unroll
            for (int e = 0; e < 8; ++e) {
                float f = q[e];
                short hi = f2bf(f);
                bhf[G][kt][e] = hi;
                blf[G][kt][e] = f2bf(f - bf2f(hi));
            }
        }
        biasv[G] = bih[li * 256 + row] + bhh[li * 256 + row];
        wihv[G]  = Wih[li * 256 + row];
    }

    // x prefetch pointers: lane's 4 batches are 4*kg..4*kg+3 (D rows)
    const float* xp[4];
    float xc[4], xn[4];
    #pragma unroll
    for (int r = 0; r < 4; ++r) {
        xp[r] = x + ((size_t)bg * 16 + kg * 4 + r) * NT;
        xc[r] = xp[r][0];
    }

    // A-fragment LDS offsets (swizzled): slot = (kt*4+kg) ^ (bq&7)
    const int ia0 = bq * 64 + (((0 + kg) ^ (bq & 7)) << 3);
    const int ia1 = bq * 64 + (((4 + kg) ^ (bq & 7)) << 3);

    // epilogue write indices: unit u = 16w+bq, batch b = 4*kg+r
    const int uu = 16 * w + bq;
    int wi[4];
    #pragma unroll
    for (int r = 0; r < 4; ++r) {
        int b = 4 * kg + r;
        wi[r] = b * 64 + ((((uu >> 3) ^ (b & 7)) << 3) | (uu & 7));
    }

    // projection roles
    const bool dop  = (w < 2);
    const int  pb   = (w & 1) * 8 + (l >> 3);   // batch 0..15 across waves 0,1
    const int  pa   = l & 7;
    const bool do63 = (w == 3) && (bq == 15);
    float pacc = 0.0f;
    float cst[4] = {0.0f, 0.0f, 0.0f, 0.0f};

    __syncthreads();

    #pragma unroll 2
    for (int t = 0; t < NT; ++t) {
        const int p = t & 1;

        if (dop && t > 0)
            pacc = fmaf(h63buf[p][pb], wl_lds[t - 1][pa], pacc);

        int t1 = (t < NT - 1) ? t + 1 : t;
        #pragma unroll
        for (int r = 0; r < 4; ++r) xn[r] = xp[r][t1];

        bf16x8 ah0 = *(const bf16x8*)&hbuf[p][0][ia0];
        bf16x8 ah1 = *(const bf16x8*)&hbuf[p][0][ia1];
        bf16x8 al0 = *(const bf16x8*)&hbuf[p][1][ia0];
        bf16x8 al1 = *(const bf16x8*)&hbuf[p][1][ia1];

        f32x4 acc[4];
        #pragma unroll
        for (int G = 0; G < 4; ++G) {
            f32x4 ini;
            #pragma unroll
            for (int r = 0; r < 4; ++r) ini[r] = fmaf(xc[r], wihv[G], biasv[G]);
            f32x4 a = __builtin_amdgcn_mfma_f32_16x16x32_bf16(ah0, bhf[G][0], ini, 0, 0, 0);
            a = __builtin_amdgcn_mfma_f32_16x16x32_bf16(ah1, bhf[G][1], a, 0, 0, 0);
            a = __builtin_amdgcn_mfma_f32_16x16x32_bf16(al0, bhf[G][0], a, 0, 0, 0);
            a = __builtin_amdgcn_mfma_f32_16x16x32_bf16(al1, bhf[G][1], a, 0, 0, 0);
            a = __builtin_amdgcn_mfma_f32_16x16x32_bf16(ah0, blf[G][0], a, 0, 0, 0);
            a = __builtin_amdgcn_mfma_f32_16x16x32_bf16(ah1, blf[G][1], a, 0, 0, 0);
            acc[G] = a;
        }

        #pragma unroll
        for (int r = 0; r < 4; ++r) {
            float iv = fsig(acc[0][r]);
            float fv = fsig(acc[1][r]);
            float gv = ftanh(acc[2][r]);
            float ov = fsig(acc[3][r]);
            cst[r] = fmaf(fv, cst[r], iv * gv);
            float hh = ov * ftanh(cst[r]);
            short hi = f2bf(hh);
            hbuf[p ^ 1][0][wi[r]] = hi;
            hbuf[p ^ 1][1][wi[r]] = f2bf(hh - bf2f(hi));
            if (do63) h63buf[p ^ 1][4 * kg + r] = hh;
            xc[r] = xn[r];
        }
        __syncthreads();
    }

    if (dop) {
        pacc = fmaf(h63buf[0][pb], wl_lds[NT - 1][pa], pacc);
        ws[((size_t)li * NB + bg * 16 + pb) * LENA + pa] = pacc;
    }
}

__global__ __launch_bounds__(256) void reduce_kernel(
    const float* __restrict__ ws, const float* __restrict__ bl, float* __restrict__ out)
{
    int tid = blockIdx.x * 256 + threadIdx.x;    // 0..1023
    if (tid >= NB * LENA) return;
    int b = tid >> 3, a = tid & 7;
    float s = bl[a];
    #pragma unroll
    for (int l2 = 0; l2 < LENA; ++l2) s += ws[((size_t)l2 * NB + b) * LENA + a];
    out[tid] = s;
}

extern "C" void kernel_launch(void* const* d_in, const int* in_sizes, int n_in,
                              void* d_out, int out_size, void* d_ws, size_t ws_size,
                              hipStream_t stream) {
    const float* x   = (const float*)d_in[0];
    const float* hn  = (const float*)d_in[1];
    const float* Wih = (const float*)d_in[2];
    const float* Whh = (const float*)d_in[3];
    const float* bih = (const float*)d_in[4];
    const float* bhh = (const float*)d_in[5];
    const float* Wl  = (const float*)d_in[6];
    const float* bl  = (const float*)d_in[7];
    float* out = (float*)d_out;
    float* ws  = (float*)d_ws;   // 8*128*8*4 = 32 KB

    lstm_mfma_kernel<<<dim3(64), dim3(256), 0, stream>>>(x, hn, Wih, Whh, bih, bhh, Wl, ws);
    reduce_kernel<<<dim3(4), dim3(256), 0, stream>>>(ws, bl, out);
}